// Round 4
// baseline (796.807 us; speedup 1.0000x reference)
//
#include <hip/hip_runtime.h>
#include <hip/hip_fp16.h>

#define BATCH 4096
#define CHB   1024    // batch chunk (caps/priors buffers sized for CHB rows)
#define NCHUNK (BATCH/CHB)
#define NCLS  4
#define INDIM 100
#define INITD 64
#define DD    164     // IN_DIM + INIT_DIM
#define MM    33      // PCAP + 1
#define TT    16
#define NOUT  16      // OUT_CAPS
#define LVS   32

// ======================= k_pre: entmax (bisection) + leaf norm =======================
// entmax15(x): x' = (x - max)/2; solve sum(clip(x'-tau,0)^2) = 1 by bisection
// (g strictly decreasing on root interval; g(-1)>=1 (max elem contributes 1), g(0)=0).
__device__ void entmax_small(const float* in, int n, float* out){
  float mx = -1e30f;
  for (int i=0;i<n;++i) mx = fmaxf(mx, in[i]);
  float lo = -1.0f, hi = 0.0f;
  for (int it=0; it<30; ++it){
    float mid = 0.5f*(lo+hi), g = 0.0f;
    for (int i=0;i<n;++i){
      float t = (in[i]-mx)*0.5f - mid;
      t = fmaxf(t, 0.0f);
      g += t*t;
    }
    if (g > 1.0f) lo = mid; else hi = mid;
  }
  float tau = 0.5f*(lo+hi);
  for (int i=0;i<n;++i){
    float t = (in[i]-mx)*0.5f - tau;
    t = fmaxf(t, 0.0f);
    out[i] = t*t;
  }
}

__global__ __launch_bounds__(64) void k_pre(const float* __restrict__ route_w,
    const float* __restrict__ m1_w, const float* __restrict__ m2_w,
    const float* __restrict__ leaves,
    __half* __restrict__ w2, float* __restrict__ mask1, float* __restrict__ mask2,
    float* __restrict__ lh_t){
  __shared__ float buf[DD*64];
  int blk = blockIdx.x, lane = threadIdx.x;
  if (blk < 132){
    // one entmax problem per lane; problem P=(m,n,t): entmax over d (stride 16 in route_w)
    int P = blk*64 + lane;
    const size_t base = (size_t)(P>>4)*(DD*16) + (size_t)(P&15);
    float mx = -1e30f;
    for (int d=0; d<DD; ++d){
      float v = route_w[base + (size_t)d*16];
      buf[d*64+lane] = v;
      mx = fmaxf(mx, v);
    }
    for (int d=0; d<DD; ++d) buf[d*64+lane] = (buf[d*64+lane]-mx)*0.5f;
    float lo=-1.0f, hi=0.0f;
    for (int it=0; it<30; ++it){
      float mid = 0.5f*(lo+hi), g=0.0f;
      for (int d=0; d<DD; ++d){
        float t = buf[d*64+lane]-mid; t = fmaxf(t,0.0f); g += t*t;
      }
      if (g>1.0f) lo=mid; else hi=mid;
    }
    float tau = 0.5f*(lo+hi);
    int m = P>>8, j = P&255;   // j = n*16 + t
    // write transposed for GEMM: w2[m][d][j], j = n*16+t
    for (int d=0; d<DD; ++d){
      float t = buf[d*64+lane]-tau; t = fmaxf(t,0.0f);
      w2[((size_t)m*DD + d)*256 + j] = __float2half(t*t);
    }
  } else {
    if (lane < 3)      entmax_small(m1_w + lane*64, 64, mask1 + lane*64);
    else if (lane < 6) entmax_small(m2_w + (lane-3)*80, 80, mask2 + (lane-3)*80);
    else if (lane >= 8 && lane < 40){
      int li = lane-8;
      float s=0.0f;
      for (int t=0;t<TT;++t){ float v=leaves[li*TT+t]; s+=v*v; }
      float dn = fmaxf(sqrtf(s), 1e-12f);
      for (int t=0;t<TT;++t) lh_t[t*32+li] = leaves[li*TT+t]/dn;  // transposed [t][l]
    }
  }
}

// ======================= k_caps: encoder (init fc, concat, caps, LayerNorm) ==========
// caps buffer is CHUNK-local: caps[bl][m][d], bl = blockIdx.x, global b = b0+bl.
__global__ __launch_bounds__(256) void k_caps(const float* __restrict__ x,
    const float* __restrict__ init_w, const float* __restrict__ init_b,
    const float* __restrict__ ln_g, const float* __restrict__ ln_b,
    const float* __restrict__ prim_fc, __half* __restrict__ caps, int b0){
  int bl = blockIdx.x, b = b0 + bl, tid = threadIdx.x;
  __shared__ float f[DD], gs[DD], bs[DD], pfs[DD*32];
  if (tid < INDIM) f[tid] = x[(size_t)b*INDIM + tid];
  if (tid < DD){ gs[tid] = ln_g[tid]; bs[tid] = ln_b[tid]; }
  for (int i = tid; i < DD*32; i += 256) pfs[i] = prim_fc[i];
  __syncthreads();
  if (tid < INITD){
    float s = init_b[tid];
    for (int k=0;k<INDIM;++k) s += f[k]*init_w[tid*INDIM+k];
    f[INDIM+tid] = s;
  }
  __syncthreads();
  int w = tid>>6, lane = tid&63;
  for (int mi = w; mi < MM; mi += 4){
    float c[3]; float sum=0.0f, sq=0.0f;
    #pragma unroll
    for (int j=0;j<3;++j){
      int d = lane + 64*j;
      float v = 0.0f;
      if (d < DD) v = (mi < 32) ? f[d]*pfs[d*32+mi] : f[d];
      c[j] = v; sum += v; sq += v*v;
    }
    #pragma unroll
    for (int off=32; off; off>>=1){ sum += __shfl_xor(sum,off); sq += __shfl_xor(sq,off); }
    float mean = sum*(1.0f/DD);
    float var  = fmaxf(sq*(1.0f/DD) - mean*mean, 0.0f);
    float rstd = rsqrtf(var + 1e-5f);
    #pragma unroll
    for (int j=0;j<3;++j){
      int d = lane + 64*j;
      if (d < DD)
        caps[(size_t)bl*(MM*DD) + mi*DD + d] = __float2half((c[j]-mean)*rstd*gs[d] + bs[d]);
    }
  }
}

// ======================= k_gemm_priors: priors[bl][m][n*16+t] (chunk-local) ===========
// per chunk: 33 GEMMs [CHB x 164] * [164 x 256]; block = 64 rows x 256 cols, thread 8x8.
#define GBM 64
#define GKC 41   // 164 = 4*41
__global__ __launch_bounds__(256) void k_gemm_priors(const __half* __restrict__ caps,
    const __half* __restrict__ w2, __half* __restrict__ priors){
  int m  = blockIdx.y;
  int b0 = blockIdx.x * GBM;          // chunk-local row
  int tid = threadIdx.x;
  int ty = tid >> 5, tx = tid & 31;   // 8 row-groups x 32 col-groups
  __shared__ float As[GKC][GBM + 4];  // stride 68: 16B-aligned float4 reads
  __shared__ float Ws[GKC][256];
  float acc[8][8];
  #pragma unroll
  for (int i=0;i<8;++i)
    #pragma unroll
    for (int j=0;j<8;++j) acc[i][j] = 0.0f;

  for (int kc = 0; kc < 4; ++kc){
    for (int i = tid; i < GKC*GBM; i += 256){
      int r = i / GKC, d = i % GKC;
      As[d][r] = __half2float(caps[(size_t)(b0 + r)*(MM*DD) + m*DD + kc*GKC + d]);
    }
    for (int i = tid; i < GKC*256; i += 256){
      int d = i >> 8, c = i & 255;
      Ws[d][c] = __half2float(w2[((size_t)m*DD + kc*GKC + d)*256 + c]);
    }
    __syncthreads();
    #pragma unroll 2
    for (int d = 0; d < GKC; ++d){
      float4 a0 = *(const float4*)&As[d][ty*8];
      float4 a1 = *(const float4*)&As[d][ty*8+4];
      float4 w0 = *(const float4*)&Ws[d][tx*8];
      float4 w1 = *(const float4*)&Ws[d][tx*8+4];
      float a[8] = {a0.x,a0.y,a0.z,a0.w,a1.x,a1.y,a1.z,a1.w};
      float wv[8] = {w0.x,w0.y,w0.z,w0.w,w1.x,w1.y,w1.z,w1.w};
      #pragma unroll
      for (int i=0;i<8;++i)
        #pragma unroll
        for (int j=0;j<8;++j) acc[i][j] += a[i]*wv[j];
    }
    __syncthreads();
  }
  for (int i=0;i<8;++i){
    union { int4 v; __half h[8]; } u;
    #pragma unroll
    for (int j=0;j<8;++j) u.h[j] = __float2half(acc[i][j]);
    *(int4*)&priors[(size_t)(b0 + ty*8 + i)*(MM*256) + m*256 + tx*8] = u.v;
  }
}

// ======================= k_route: votes -> dis -> softmax -> hidden LN -> pred/hsel ===
__global__ __launch_bounds__(256) void k_route(const __half* __restrict__ priors,
    const float* __restrict__ lh_t, const float* __restrict__ thr_in,
    const float* __restrict__ cg, const float* __restrict__ cbv,
    const float* __restrict__ y, float* __restrict__ out_pred, float* __restrict__ hsel,
    int b0){
  int bl = blockIdx.x, b = b0 + bl, tid = threadIdx.x;
  __shared__ __half pr[MM*256];
  __shared__ float lhs[512];           // [t][l]
  __shared__ float votes[8*MM*32];
  __shared__ float vmean[8*32];
  __shared__ float wp[8*MM];
  __shared__ float hid[16*16];
  __shared__ float nrm[16];
  __shared__ float yw[4];
  {
    const unsigned* pbw = (const unsigned*)(priors + (size_t)bl*(MM*256));
    unsigned* prw = (unsigned*)pr;
    for (int i = tid; i < (MM*256)/2; i += 256) prw[i] = pbw[i];
  }
  for (int i = tid; i < 512; i += 256) lhs[i] = lh_t[i];
  if (tid < 4) yw[tid] = y[(size_t)b*4 + tid];
  __syncthreads();

  for (int nc = 0; nc < 2; ++nc){
    int nl = tid >> 5, l = tid & 31, n = nc*8 + nl;
    // votes[m][l] = sigmoid(sum_t lh[l][t]*priors[m][n][t])
    for (int m=0;m<MM;++m){
      float s = 0.0f;
      const __half* p0 = &pr[m*256 + n*16];
      #pragma unroll
      for (int t=0;t<TT;++t) s += lhs[t*32+l]*__half2float(p0[t]);
      votes[(nl*MM+m)*32 + l] = 1.0f/(1.0f+__expf(-s));
    }
    __syncthreads();
    {
      float s = 0.0f;
      for (int m=0;m<MM;++m) s += votes[(nl*MM+m)*32 + l];
      vmean[nl*32+l] = s*(1.0f/MM);
    }
    __syncthreads();
    // NOTE: 8*MM = 264 > 256 threads — grid-stride required
    for (int i = tid; i < 8*MM; i += 256){
      int nl2 = i/MM, m = i%MM, n2 = nc*8 + nl2;
      float s = 0.0f;
      for (int l2=0;l2<32;++l2){
        float dd = votes[(nl2*MM+m)*32+l2] - vmean[nl2*32+l2];
        s += dd*dd;
      }
      float dis = s*(1.0f/32);
      float th = thr_in[m*NOUT + n2];
      wp[nl2*MM+m] = fmaxf(th*th - dis, 0.0f);
    }
    __syncthreads();
    if (tid < 8){
      float mx = -1e30f;
      for (int m=0;m<MM;++m) mx = fmaxf(mx, wp[tid*MM+m]);
      float s = 0.0f;
      for (int m=0;m<MM;++m){ float e = expf(wp[tid*MM+m]-mx); wp[tid*MM+m] = e; s += e; }
      float inv = 1.0f/s;
      for (int m=0;m<MM;++m) wp[tid*MM+m] *= inv;
    }
    __syncthreads();
    if (tid < 128){
      int nl3 = tid >> 4, t = tid & 15, n3 = nc*8 + nl3;
      float s = 0.0f;
      for (int m=0;m<MM;++m) s += wp[nl3*MM+m]*__half2float(pr[m*256 + n3*16 + t]);
      hid[n3*16+t] = s;
    }
    __syncthreads();
  }
  // LayerNorm over T per n, norms
  if (tid < 16){
    float s=0.0f, q=0.0f;
    for (int t=0;t<TT;++t){ float v=hid[tid*16+t]; s+=v; q+=v*v; }
    float mean = s*(1.0f/TT);
    float var  = fmaxf(q*(1.0f/TT)-mean*mean, 0.0f);
    float rstd = rsqrtf(var + 1e-5f);
    float nn = 0.0f;
    for (int t=0;t<TT;++t){
      float v = (hid[tid*16+t]-mean)*rstd*cg[t] + cbv[t];
      hid[tid*16+t] = v; nn += v*v;
    }
    nrm[tid] = sqrtf(nn);
  }
  __syncthreads();
  if (tid < 4)
    out_pred[(size_t)b*4 + tid] = nrm[tid*4+0]+nrm[tid*4+1]+nrm[tid*4+2]+nrm[tid*4+3];
  if (tid < 64){
    int s2 = tid >> 4, t = tid & 15;
    float v = 0.0f;
    #pragma unroll
    for (int c=0;c<4;++c) v += yw[c]*hid[(s2*4+c)*16 + t];
    hsel[(size_t)b*64 + tid] = v;
  }
}

// ======================= decoder =======================
__global__ __launch_bounds__(256) void k_h1(const float* __restrict__ hsel,
    const float* __restrict__ mask1, const float* __restrict__ fc1_w,
    const float* __restrict__ fc1_b, float* __restrict__ h1){
  int idx = blockIdx.x*256 + threadIdx.x;
  if (idx >= BATCH*96) return;
  int b = idx/96, j = idx%96, p = j>>5;
  float s = fc1_b[j];
  const float* hs = hsel + (size_t)b*64;
  const float* mk = mask1 + p*64;
  const float* wr = fc1_w + (size_t)j*64;
  for (int d=0; d<64; ++d) s += mk[d]*hs[d]*wr[d];
  h1[idx] = s;
}

__global__ __launch_bounds__(256) void k_stats(const float* __restrict__ h,
    float* __restrict__ stats, int F){
  int vb = blockIdx.x / F, j = blockIdx.x % F;
  float v = h[(size_t)(vb*256 + threadIdx.x)*F + j];
  float s = v, q = v*v;
  #pragma unroll
  for (int off=32; off; off>>=1){ s += __shfl_xor(s,off); q += __shfl_xor(q,off); }
  __shared__ float ps[4], pq[4];
  int w = threadIdx.x >> 6;
  if ((threadIdx.x & 63) == 0){ ps[w]=s; pq[w]=q; }
  __syncthreads();
  if (threadIdx.x == 0){
    float ss = ps[0]+ps[1]+ps[2]+ps[3];
    float qq = pq[0]+pq[1]+pq[2]+pq[3];
    float mean = ss*(1.0f/256);
    float var  = fmaxf(qq*(1.0f/256) - mean*mean, 0.0f);
    stats[(size_t)blockIdx.x*2]   = mean;
    stats[(size_t)blockIdx.x*2+1] = rsqrtf(var + 1e-5f);
  }
}

__global__ __launch_bounds__(192) void k_out1h2(const float* __restrict__ hsel,
    const float* __restrict__ h1, const float* __restrict__ stats1,
    const float* __restrict__ bn1g, const float* __restrict__ bn1b,
    const float* __restrict__ mask2, const float* __restrict__ fc2_w,
    const float* __restrict__ fc2_b, float* __restrict__ h2raw){
  int b = blockIdx.x, tid = threadIdx.x, vb = b >> 8;
  __shared__ float h2s[80];
  if (tid < 64) h2s[tid] = hsel[(size_t)b*64 + tid];
  if (tid < 16){
    float s = 0.0f;
    for (int p=0;p<3;++p){
      int ja = p*32 + tid, jb = ja + 16;
      float ha = (h1[(size_t)b*96+ja]-stats1[(vb*96+ja)*2])*stats1[(vb*96+ja)*2+1]*bn1g[ja] + bn1b[ja];
      float hb = (h1[(size_t)b*96+jb]-stats1[(vb*96+jb)*2])*stats1[(vb*96+jb)*2+1]*bn1g[jb] + bn1b[jb];
      float sg = 1.0f/(1.0f+expf(-ha));
      s += fmaxf(sg*hb, 0.0f);
    }
    h2s[64+tid] = s;
  }
  __syncthreads();
  int p = tid >> 6;
  float s = fc2_b[tid];
  const float* mk = mask2 + p*80;
  const float* wr = fc2_w + (size_t)tid*80;
  for (int d=0; d<80; ++d) s += mk[d]*h2s[d]*wr[d];
  h2raw[(size_t)b*192 + tid] = s;
}

__global__ __launch_bounds__(128) void k_final(const float* __restrict__ h2raw,
    const float* __restrict__ stats2, const float* __restrict__ bn2g,
    const float* __restrict__ bn2b, const float* __restrict__ dec_w,
    const float* __restrict__ dec_b, float* __restrict__ out_rec){
  int b = blockIdx.x, tid = threadIdx.x, vb = b >> 8;
  __shared__ float o2[32];
  if (tid < 32){
    float s = 0.0f;
    for (int p=0;p<3;++p){
      int ja = p*64 + tid, jb = ja + 32;
      float ha = (h2raw[(size_t)b*192+ja]-stats2[(vb*192+ja)*2])*stats2[(vb*192+ja)*2+1]*bn2g[ja] + bn2b[ja];
      float hb = (h2raw[(size_t)b*192+jb]-stats2[(vb*192+jb)*2])*stats2[(vb*192+jb)*2+1]*bn2g[jb] + bn2b[jb];
      float sg = 1.0f/(1.0f+expf(-ha));
      s += fmaxf(sg*hb, 0.0f);
    }
    o2[tid] = s;
  }
  __syncthreads();
  if (tid < INDIM){
    float r = dec_b[tid];
    #pragma unroll
    for (int o=0;o<32;++o) r += o2[o]*dec_w[tid*32+o];
    out_rec[(size_t)b*INDIM + tid] = r;
  }
}

// ======================= launch =======================
extern "C" void kernel_launch(void* const* d_in, const int* in_sizes, int n_in,
                              void* d_out, int out_size, void* d_ws, size_t ws_size,
                              hipStream_t stream){
  const float* x      = (const float*)d_in[0];
  const float* y      = (const float*)d_in[1];
  const float* init_w = (const float*)d_in[2];
  const float* init_b = (const float*)d_in[3];
  const float* eg     = (const float*)d_in[4];
  const float* ebv    = (const float*)d_in[5];
  const float* pf     = (const float*)d_in[6];
  const float* rw     = (const float*)d_in[7];
  const float* thr    = (const float*)d_in[8];
  const float* lv     = (const float*)d_in[9];
  const float* cg     = (const float*)d_in[10];
  const float* cbv    = (const float*)d_in[11];
  const float* m1w    = (const float*)d_in[12];
  const float* f1w    = (const float*)d_in[13];
  const float* f1b    = (const float*)d_in[14];
  const float* g1     = (const float*)d_in[15];
  const float* b1     = (const float*)d_in[16];
  const float* m2w    = (const float*)d_in[17];
  const float* f2w    = (const float*)d_in[18];
  const float* f2b    = (const float*)d_in[19];
  const float* g2     = (const float*)d_in[20];
  const float* b2v    = (const float*)d_in[21];
  const float* dw     = (const float*)d_in[22];
  const float* db     = (const float*)d_in[23];
  char* ws = (char*)d_ws;
  float* out = (float*)d_out;

  auto al = [](size_t v){ return (v + 255) & ~(size_t)255; };
  size_t o = 0;
  size_t o_w2   = o; o = al(o + (size_t)MM*DD*256*sizeof(__half));     // 2.77 MB
  size_t o_caps = o; o = al(o + (size_t)CHB*MM*DD*sizeof(__half));     // 11.1 MB (chunk)
  size_t o_pri  = o; o = al(o + (size_t)CHB*MM*256*sizeof(__half));    // 17.3 MB (chunk)
  size_t o_m1   = o; o = al(o + 3*64*sizeof(float));
  size_t o_m2   = o; o = al(o + 3*80*sizeof(float));
  size_t o_lh   = o; o = al(o + 512*sizeof(float));
  size_t o_hsel = o; o = al(o + (size_t)BATCH*64*sizeof(float));
  size_t o_h1   = o; o = al(o + (size_t)BATCH*96*sizeof(float));
  size_t o_s1   = o; o = al(o + 16*96*2*sizeof(float));
  size_t o_h2   = o; o = al(o + (size_t)BATCH*192*sizeof(float));
  size_t o_s2   = o; o = al(o + 16*192*2*sizeof(float));
  (void)ws_size; (void)in_sizes; (void)n_in; (void)out_size;
  // total ~37 MB

  k_pre<<<dim3(133), dim3(64), 0, stream>>>(rw, m1w, m2w, lv,
      (__half*)(ws+o_w2), (float*)(ws+o_m1), (float*)(ws+o_m2), (float*)(ws+o_lh));

  for (int c = 0; c < NCHUNK; ++c){
    int b0 = c*CHB;
    k_caps<<<dim3(CHB), dim3(256), 0, stream>>>(x, init_w, init_b, eg, ebv, pf,
        (__half*)(ws+o_caps), b0);
    k_gemm_priors<<<dim3(CHB/GBM, MM), dim3(256), 0, stream>>>(
        (const __half*)(ws+o_caps), (const __half*)(ws+o_w2), (__half*)(ws+o_pri));
    k_route<<<dim3(CHB), dim3(256), 0, stream>>>((const __half*)(ws+o_pri),
        (const float*)(ws+o_lh), thr, cg, cbv, y, out, (float*)(ws+o_hsel), b0);
  }

  k_h1<<<dim3((BATCH*96)/256), dim3(256), 0, stream>>>((const float*)(ws+o_hsel),
      (const float*)(ws+o_m1), f1w, f1b, (float*)(ws+o_h1));
  k_stats<<<dim3(16*96), dim3(256), 0, stream>>>((const float*)(ws+o_h1),
      (float*)(ws+o_s1), 96);
  k_out1h2<<<dim3(BATCH), dim3(192), 0, stream>>>((const float*)(ws+o_hsel),
      (const float*)(ws+o_h1), (const float*)(ws+o_s1), g1, b1,
      (const float*)(ws+o_m2), f2w, f2b, (float*)(ws+o_h2));
  k_stats<<<dim3(16*192), dim3(256), 0, stream>>>((const float*)(ws+o_h2),
      (float*)(ws+o_s2), 192);
  k_final<<<dim3(BATCH), dim3(128), 0, stream>>>((const float*)(ws+o_h2),
      (const float*)(ws+o_s2), g2, b2v, dw, db, out + (size_t)BATCH*NCLS);
}

// Round 5
// 606.787 us; speedup vs baseline: 1.3132x; 1.3132x over previous
//
#include <hip/hip_runtime.h>
#include <hip/hip_fp16.h>

#define BATCH 4096
#define CHB   1024    // batch chunk
#define NCHUNK (BATCH/CHB)
#define NCLS  4
#define INDIM 100
#define INITD 64
#define DD    164     // IN_DIM + INIT_DIM
#define DDP   192     // K padded to 6*32 for MFMA
#define MM    33      // PCAP + 1
#define TT    16
#define NOUT  16      // OUT_CAPS

typedef _Float16 f16;
typedef f16 f16x8 __attribute__((ext_vector_type(8)));
typedef float f32x4 __attribute__((ext_vector_type(4)));

// ======================= k_pre: entmax (bisection) + leaf norm =======================
// entmax15(x): x' = (x - max)/2; solve sum(clip(x'-tau,0)^2) = 1 by bisection.
__device__ void entmax_small(const float* in, int n, float* out){
  float mx = -1e30f;
  for (int i=0;i<n;++i) mx = fmaxf(mx, in[i]);
  float lo = -1.0f, hi = 0.0f;
  for (int it=0; it<30; ++it){
    float mid = 0.5f*(lo+hi), g = 0.0f;
    for (int i=0;i<n;++i){
      float t = (in[i]-mx)*0.5f - mid;
      t = fmaxf(t, 0.0f);
      g += t*t;
    }
    if (g > 1.0f) lo = mid; else hi = mid;
  }
  float tau = 0.5f*(lo+hi);
  for (int i=0;i<n;++i){
    float t = (in[i]-mx)*0.5f - tau;
    t = fmaxf(t, 0.0f);
    out[i] = t*t;
  }
}

// blocks 0..527: blk = m*16+n; 16 entmax problems (one per t), one per 16-lane group.
// group = lanes with equal (l&3) within a wave: t = (tid>>6)*4 + (l&3), lg = l>>2.
// Writes w2t[m][j][DDP] (j = n*16+t) zero-padded to DDP.
__global__ __launch_bounds__(256) void k_pre(const float* __restrict__ route_w,
    const float* __restrict__ m1_w, const float* __restrict__ m2_w,
    const float* __restrict__ leaves,
    __half* __restrict__ w2t, float* __restrict__ mask1, float* __restrict__ mask2,
    float* __restrict__ lh_t){
  int blk = blockIdx.x, tid = threadIdx.x;
  if (blk < 528){
    const float* base = route_w + (size_t)blk*DD*16;   // [164][16] slab for (m,n)
    int l  = tid & 63;
    int t  = (tid>>6)*4 + (l&3);
    int lg = l>>2;                                     // d = lg + 16*i
    float v[11];
    float mx = -1e30f;
    #pragma unroll
    for (int i=0;i<11;++i){
      int d = lg + 16*i;
      v[i] = (d < DD) ? base[d*16 + t] : -1e30f;
      mx = fmaxf(mx, v[i]);
    }
    #pragma unroll
    for (int msk=4; msk<=32; msk<<=1) mx = fmaxf(mx, __shfl_xor(mx, msk));
    #pragma unroll
    for (int i=0;i<11;++i) v[i] = (v[i]-mx)*0.5f;      // invalid lanes -> huge negative
    float lo=-1.0f, hi=0.0f;
    for (int it=0; it<30; ++it){
      float mid = 0.5f*(lo+hi), g=0.0f;
      #pragma unroll
      for (int i=0;i<11;++i){ float tv = fmaxf(v[i]-mid, 0.0f); g += tv*tv; }
      #pragma unroll
      for (int msk=4; msk<=32; msk<<=1) g += __shfl_xor(g, msk);  // butterfly: identical in group
      if (g > 1.0f) lo = mid; else hi = mid;           // uniform branch
    }
    float tau = 0.5f*(lo+hi);
    __half* wout = w2t + (size_t)(blk*16 + t)*DDP;
    #pragma unroll
    for (int i=0;i<12;++i){
      int d = lg + 16*i;
      if (d < DDP){
        float tv = 0.0f;
        if (i < 11 && d < DD){ tv = fmaxf(v[i]-tau, 0.0f); }
        wout[d] = __float2half(tv*tv);
      }
    }
  } else {
    if (tid < 3)      entmax_small(m1_w + tid*64, 64, mask1 + tid*64);
    else if (tid < 6) entmax_small(m2_w + (tid-3)*80, 80, mask2 + (tid-3)*80);
    else if (tid >= 8 && tid < 40){
      int li = tid-8;
      float s=0.0f;
      for (int t=0;t<TT;++t){ float vv=leaves[li*TT+t]; s+=vv*vv; }
      float dn = fmaxf(sqrtf(s), 1e-12f);
      for (int t=0;t<TT;++t) lh_t[t*32+li] = leaves[li*TT+t]/dn;  // transposed [t][l]
    }
  }
}

// ======================= k_caps: encoder -> caps_t[m][bl][DDP] (f16, zero-padded) ====
__global__ __launch_bounds__(256) void k_caps(const float* __restrict__ x,
    const float* __restrict__ init_w, const float* __restrict__ init_b,
    const float* __restrict__ ln_g, const float* __restrict__ ln_b,
    const float* __restrict__ prim_fc, __half* __restrict__ caps_t, int b0){
  int bl = blockIdx.x, b = b0 + bl, tid = threadIdx.x;
  __shared__ float f[DD], gs[DD], bs[DD], pfs[DD*32];
  if (tid < INDIM) f[tid] = x[(size_t)b*INDIM + tid];
  if (tid < DD){ gs[tid] = ln_g[tid]; bs[tid] = ln_b[tid]; }
  for (int i = tid; i < DD*32; i += 256) pfs[i] = prim_fc[i];
  __syncthreads();
  if (tid < INITD){
    float s = init_b[tid];
    for (int k=0;k<INDIM;++k) s += f[k]*init_w[tid*INDIM+k];
    f[INDIM+tid] = s;
  }
  __syncthreads();
  int w = tid>>6, lane = tid&63;
  for (int mi = w; mi < MM; mi += 4){
    float c[3]; float sum=0.0f, sq=0.0f;
    #pragma unroll
    for (int j=0;j<3;++j){
      int d = lane + 64*j;
      float v = 0.0f;
      if (d < DD) v = (mi < 32) ? f[d]*pfs[d*32+mi] : f[d];
      c[j] = v; sum += v; sq += v*v;
    }
    #pragma unroll
    for (int off=32; off; off>>=1){ sum += __shfl_xor(sum,off); sq += __shfl_xor(sq,off); }
    float mean = sum*(1.0f/DD);
    float var  = fmaxf(sq*(1.0f/DD) - mean*mean, 0.0f);
    float rstd = rsqrtf(var + 1e-5f);
    #pragma unroll
    for (int j=0;j<3;++j){
      int d = lane + 64*j;   // covers 0..191 exactly
      float o = (d < DD) ? ((c[j]-mean)*rstd*gs[d] + bs[d]) : 0.0f;
      caps_t[((size_t)mi*CHB + bl)*DDP + d] = __float2half(o);
    }
  }
}

// ======================= k_gemm_mfma: priors[bl][m][256] via 16x16x32 f16 MFMA =======
// grid (CHB/64, 33), block 256 = 4 waves. Tile 64 rows x 256 cols, K = 192 (6x32).
__global__ __launch_bounds__(256) void k_gemm_mfma(const f16* __restrict__ caps_t,
    const f16* __restrict__ w2t, __half* __restrict__ priors){
  int m = blockIdx.y, b0 = blockIdx.x*64;
  int tid = threadIdx.x;
  int wave = tid>>6, lane = tid&63;
  __shared__ f16 Al[64][40];     // row stride 80 B (bank-spread, 16B aligned)
  __shared__ f16 Wl[256][40];
  f32x4 acc[4][4];
  #pragma unroll
  for (int i=0;i<4;++i)
    #pragma unroll
    for (int j=0;j<4;++j) acc[i][j] = (f32x4){0.f,0.f,0.f,0.f};

  int ar = tid>>2, ac0 = (tid&3)*8;    // A staging: 64 rows x 4 chunks
  int rg = lane&15, kg = lane>>4;      // fragment row / k-group

  for (int kc = 0; kc < 6; ++kc){
    *(uint4*)&Al[ar][ac0] =
        *(const uint4*)&caps_t[((size_t)m*CHB + b0 + ar)*DDP + kc*32 + ac0];
    #pragma unroll
    for (int c=0;c<4;++c)
      *(uint4*)&Wl[tid][c*8] =
          *(const uint4*)&w2t[((size_t)m*256 + tid)*DDP + kc*32 + c*8];
    __syncthreads();
    f16x8 a[4], bf[4];
    #pragma unroll
    for (int i=0;i<4;++i) a[i]  = *(const f16x8*)&Al[i*16 + rg][kg*8];
    #pragma unroll
    for (int j=0;j<4;++j) bf[j] = *(const f16x8*)&Wl[wave*64 + j*16 + rg][kg*8];
    #pragma unroll
    for (int i=0;i<4;++i)
      #pragma unroll
      for (int j=0;j<4;++j)
        acc[i][j] = __builtin_amdgcn_mfma_f32_16x16x32_f16(a[i], bf[j], acc[i][j], 0, 0, 0);
    __syncthreads();
  }
  int rg4 = kg*4, cc = rg;             // D: row = 4*(l>>4)+reg, col = l&15
  #pragma unroll
  for (int i=0;i<4;++i)
    #pragma unroll
    for (int j=0;j<4;++j)
      #pragma unroll
      for (int r=0;r<4;++r)
        priors[(size_t)(b0 + i*16 + rg4 + r)*(MM*256) + m*256 + wave*64 + j*16 + cc]
            = __float2half(acc[i][j][r]);
}

// ======================= k_route: votes -> dis -> softmax -> hidden LN -> pred/hsel ===
__global__ __launch_bounds__(256) void k_route(const __half* __restrict__ priors,
    const float* __restrict__ lh_t, const float* __restrict__ thr_in,
    const float* __restrict__ cg, const float* __restrict__ cbv,
    const float* __restrict__ y, float* __restrict__ out_pred, float* __restrict__ hsel,
    int b0){
  int bl = blockIdx.x, b = b0 + bl, tid = threadIdx.x;
  __shared__ __half pr[MM*256];
  __shared__ float lhs[512];           // [t][l]
  __shared__ float votes[8*MM*32];
  __shared__ float vmean[8*32];
  __shared__ float wp[8*MM];
  __shared__ float hid[16*16];
  __shared__ float nrm[16];
  __shared__ float yw[4];
  {
    const unsigned* pbw = (const unsigned*)(priors + (size_t)bl*(MM*256));
    unsigned* prw = (unsigned*)pr;
    for (int i = tid; i < (MM*256)/2; i += 256) prw[i] = pbw[i];
  }
  for (int i = tid; i < 512; i += 256) lhs[i] = lh_t[i];
  if (tid < 4) yw[tid] = y[(size_t)b*4 + tid];
  __syncthreads();

  for (int nc = 0; nc < 2; ++nc){
    int nl = tid >> 5, l = tid & 31, n = nc*8 + nl;
    for (int m=0;m<MM;++m){
      float s = 0.0f;
      const __half* p0 = &pr[m*256 + n*16];
      #pragma unroll
      for (int t=0;t<TT;++t) s += lhs[t*32+l]*__half2float(p0[t]);
      votes[(nl*MM+m)*32 + l] = 1.0f/(1.0f+__expf(-s));
    }
    __syncthreads();
    {
      float s = 0.0f;
      for (int m=0;m<MM;++m) s += votes[(nl*MM+m)*32 + l];
      vmean[nl*32+l] = s*(1.0f/MM);
    }
    __syncthreads();
    // NOTE: 8*MM = 264 > 256 threads — grid-stride required
    for (int i = tid; i < 8*MM; i += 256){
      int nl2 = i/MM, m = i%MM, n2 = nc*8 + nl2;
      float s = 0.0f;
      for (int l2=0;l2<32;++l2){
        float dd = votes[(nl2*MM+m)*32+l2] - vmean[nl2*32+l2];
        s += dd*dd;
      }
      float dis = s*(1.0f/32);
      float th = thr_in[m*NOUT + n2];
      wp[nl2*MM+m] = fmaxf(th*th - dis, 0.0f);
    }
    __syncthreads();
    if (tid < 8){
      float mx = -1e30f;
      for (int m=0;m<MM;++m) mx = fmaxf(mx, wp[tid*MM+m]);
      float s = 0.0f;
      for (int m=0;m<MM;++m){ float e = expf(wp[tid*MM+m]-mx); wp[tid*MM+m] = e; s += e; }
      float inv = 1.0f/s;
      for (int m=0;m<MM;++m) wp[tid*MM+m] *= inv;
    }
    __syncthreads();
    if (tid < 128){
      int nl3 = tid >> 4, t = tid & 15, n3 = nc*8 + nl3;
      float s = 0.0f;
      for (int m=0;m<MM;++m) s += wp[nl3*MM+m]*__half2float(pr[m*256 + n3*16 + t]);
      hid[n3*16+t] = s;
    }
    __syncthreads();
  }
  if (tid < 16){
    float s=0.0f, q=0.0f;
    for (int t=0;t<TT;++t){ float v=hid[tid*16+t]; s+=v; q+=v*v; }
    float mean = s*(1.0f/TT);
    float var  = fmaxf(q*(1.0f/TT)-mean*mean, 0.0f);
    float rstd = rsqrtf(var + 1e-5f);
    float nn = 0.0f;
    for (int t=0;t<TT;++t){
      float v = (hid[tid*16+t]-mean)*rstd*cg[t] + cbv[t];
      hid[tid*16+t] = v; nn += v*v;
    }
    nrm[tid] = sqrtf(nn);
  }
  __syncthreads();
  if (tid < 4)
    out_pred[(size_t)b*4 + tid] = nrm[tid*4+0]+nrm[tid*4+1]+nrm[tid*4+2]+nrm[tid*4+3];
  if (tid < 64){
    int s2 = tid >> 4, t = tid & 15;
    float v = 0.0f;
    #pragma unroll
    for (int c=0;c<4;++c) v += yw[c]*hid[(s2*4+c)*16 + t];
    hsel[(size_t)b*64 + tid] = v;
  }
}

// ======================= decoder =======================
__global__ __launch_bounds__(256) void k_h1(const float* __restrict__ hsel,
    const float* __restrict__ mask1, const float* __restrict__ fc1_w,
    const float* __restrict__ fc1_b, float* __restrict__ h1){
  int idx = blockIdx.x*256 + threadIdx.x;
  if (idx >= BATCH*96) return;
  int b = idx/96, j = idx%96, p = j>>5;
  float s = fc1_b[j];
  const float* hs = hsel + (size_t)b*64;
  const float* mk = mask1 + p*64;
  const float* wr = fc1_w + (size_t)j*64;
  for (int d=0; d<64; ++d) s += mk[d]*hs[d]*wr[d];
  h1[idx] = s;
}

__global__ __launch_bounds__(256) void k_stats(const float* __restrict__ h,
    float* __restrict__ stats, int F){
  int vb = blockIdx.x / F, j = blockIdx.x % F;
  float v = h[(size_t)(vb*256 + threadIdx.x)*F + j];
  float s = v, q = v*v;
  #pragma unroll
  for (int off=32; off; off>>=1){ s += __shfl_xor(s,off); q += __shfl_xor(q,off); }
  __shared__ float ps[4], pq[4];
  int w = threadIdx.x >> 6;
  if ((threadIdx.x & 63) == 0){ ps[w]=s; pq[w]=q; }
  __syncthreads();
  if (threadIdx.x == 0){
    float ss = ps[0]+ps[1]+ps[2]+ps[3];
    float qq = pq[0]+pq[1]+pq[2]+pq[3];
    float mean = ss*(1.0f/256);
    float var  = fmaxf(qq*(1.0f/256) - mean*mean, 0.0f);
    stats[(size_t)blockIdx.x*2]   = mean;
    stats[(size_t)blockIdx.x*2+1] = rsqrtf(var + 1e-5f);
  }
}

__global__ __launch_bounds__(192) void k_out1h2(const float* __restrict__ hsel,
    const float* __restrict__ h1, const float* __restrict__ stats1,
    const float* __restrict__ bn1g, const float* __restrict__ bn1b,
    const float* __restrict__ mask2, const float* __restrict__ fc2_w,
    const float* __restrict__ fc2_b, float* __restrict__ h2raw){
  int b = blockIdx.x, tid = threadIdx.x, vb = b >> 8;
  __shared__ float h2s[80];
  if (tid < 64) h2s[tid] = hsel[(size_t)b*64 + tid];
  if (tid < 16){
    float s = 0.0f;
    for (int p=0;p<3;++p){
      int ja = p*32 + tid, jb = ja + 16;
      float ha = (h1[(size_t)b*96+ja]-stats1[(vb*96+ja)*2])*stats1[(vb*96+ja)*2+1]*bn1g[ja] + bn1b[ja];
      float hb = (h1[(size_t)b*96+jb]-stats1[(vb*96+jb)*2])*stats1[(vb*96+jb)*2+1]*bn1g[jb] + bn1b[jb];
      float sg = 1.0f/(1.0f+expf(-ha));
      s += fmaxf(sg*hb, 0.0f);
    }
    h2s[64+tid] = s;
  }
  __syncthreads();
  int p = tid >> 6;
  float s = fc2_b[tid];
  const float* mk = mask2 + p*80;
  const float* wr = fc2_w + (size_t)tid*80;
  for (int d=0; d<80; ++d) s += mk[d]*h2s[d]*wr[d];
  h2raw[(size_t)b*192 + tid] = s;
}

__global__ __launch_bounds__(128) void k_final(const float* __restrict__ h2raw,
    const float* __restrict__ stats2, const float* __restrict__ bn2g,
    const float* __restrict__ bn2b, const float* __restrict__ dec_w,
    const float* __restrict__ dec_b, float* __restrict__ out_rec){
  int b = blockIdx.x, tid = threadIdx.x, vb = b >> 8;
  __shared__ float o2[32];
  if (tid < 32){
    float s = 0.0f;
    for (int p=0;p<3;++p){
      int ja = p*64 + tid, jb = ja + 32;
      float ha = (h2raw[(size_t)b*192+ja]-stats2[(vb*192+ja)*2])*stats2[(vb*192+ja)*2+1]*bn2g[ja] + bn2b[ja];
      float hb = (h2raw[(size_t)b*192+jb]-stats2[(vb*192+jb)*2])*stats2[(vb*192+jb)*2+1]*bn2g[jb] + bn2b[jb];
      float sg = 1.0f/(1.0f+expf(-ha));
      s += fmaxf(sg*hb, 0.0f);
    }
    o2[tid] = s;
  }
  __syncthreads();
  if (tid < INDIM){
    float r = dec_b[tid];
    #pragma unroll
    for (int o=0;o<32;++o) r += o2[o]*dec_w[tid*32+o];
    out_rec[(size_t)b*INDIM + tid] = r;
  }
}

// ======================= launch =======================
extern "C" void kernel_launch(void* const* d_in, const int* in_sizes, int n_in,
                              void* d_out, int out_size, void* d_ws, size_t ws_size,
                              hipStream_t stream){
  const float* x      = (const float*)d_in[0];
  const float* y      = (const float*)d_in[1];
  const float* init_w = (const float*)d_in[2];
  const float* init_b = (const float*)d_in[3];
  const float* eg     = (const float*)d_in[4];
  const float* ebv    = (const float*)d_in[5];
  const float* pf     = (const float*)d_in[6];
  const float* rw     = (const float*)d_in[7];
  const float* thr    = (const float*)d_in[8];
  const float* lv     = (const float*)d_in[9];
  const float* cg     = (const float*)d_in[10];
  const float* cbv    = (const float*)d_in[11];
  const float* m1w    = (const float*)d_in[12];
  const float* f1w    = (const float*)d_in[13];
  const float* f1b    = (const float*)d_in[14];
  const float* g1     = (const float*)d_in[15];
  const float* b1     = (const float*)d_in[16];
  const float* m2w    = (const float*)d_in[17];
  const float* f2w    = (const float*)d_in[18];
  const float* f2b    = (const float*)d_in[19];
  const float* g2     = (const float*)d_in[20];
  const float* b2v    = (const float*)d_in[21];
  const float* dw     = (const float*)d_in[22];
  const float* db     = (const float*)d_in[23];
  char* ws = (char*)d_ws;
  float* out = (float*)d_out;

  auto al = [](size_t v){ return (v + 255) & ~(size_t)255; };
  size_t o = 0;
  size_t o_w2   = o; o = al(o + (size_t)MM*256*DDP*sizeof(__half));    // 3.2 MB
  size_t o_caps = o; o = al(o + (size_t)MM*CHB*DDP*sizeof(__half));    // 13 MB (chunk)
  size_t o_pri  = o; o = al(o + (size_t)CHB*MM*256*sizeof(__half));    // 17.3 MB (chunk)
  size_t o_m1   = o; o = al(o + 3*64*sizeof(float));
  size_t o_m2   = o; o = al(o + 3*80*sizeof(float));
  size_t o_lh   = o; o = al(o + 512*sizeof(float));
  size_t o_hsel = o; o = al(o + (size_t)BATCH*64*sizeof(float));
  size_t o_h1   = o; o = al(o + (size_t)BATCH*96*sizeof(float));
  size_t o_s1   = o; o = al(o + 16*96*2*sizeof(float));
  size_t o_h2   = o; o = al(o + (size_t)BATCH*192*sizeof(float));
  size_t o_s2   = o; o = al(o + 16*192*2*sizeof(float));
  (void)ws_size; (void)in_sizes; (void)n_in; (void)out_size;
  // total ~41 MB

  k_pre<<<dim3(529), dim3(256), 0, stream>>>(rw, m1w, m2w, lv,
      (__half*)(ws+o_w2), (float*)(ws+o_m1), (float*)(ws+o_m2), (float*)(ws+o_lh));

  for (int c = 0; c < NCHUNK; ++c){
    int b0 = c*CHB;
    k_caps<<<dim3(CHB), dim3(256), 0, stream>>>(x, init_w, init_b, eg, ebv, pf,
        (__half*)(ws+o_caps), b0);
    k_gemm_mfma<<<dim3(CHB/64, MM), dim3(256), 0, stream>>>(
        (const f16*)(ws+o_caps), (const f16*)(ws+o_w2), (__half*)(ws+o_pri));
    k_route<<<dim3(CHB), dim3(256), 0, stream>>>((const __half*)(ws+o_pri),
        (const float*)(ws+o_lh), thr, cg, cbv, y, out, (float*)(ws+o_hsel), b0);
  }

  k_h1<<<dim3((BATCH*96)/256), dim3(256), 0, stream>>>((const float*)(ws+o_hsel),
      (const float*)(ws+o_m1), f1w, f1b, (float*)(ws+o_h1));
  k_stats<<<dim3(16*96), dim3(256), 0, stream>>>((const float*)(ws+o_h1),
      (float*)(ws+o_s1), 96);
  k_out1h2<<<dim3(BATCH), dim3(192), 0, stream>>>((const float*)(ws+o_hsel),
      (const float*)(ws+o_h1), (const float*)(ws+o_s1), g1, b1,
      (const float*)(ws+o_m2), f2w, f2b, (float*)(ws+o_h2));
  k_stats<<<dim3(16*192), dim3(256), 0, stream>>>((const float*)(ws+o_h2),
      (float*)(ws+o_s2), 192);
  k_final<<<dim3(BATCH), dim3(128), 0, stream>>>((const float*)(ws+o_h2),
      (const float*)(ws+o_s2), g2, b2v, dw, db, out + (size_t)BATCH*NCLS);
}